// Round 5
// baseline (336.181 us; speedup 1.0000x reference)
//
#include <hip/hip_runtime.h>
#include <cstdint>
#include <cstddef>

// Problem dims
#define NB 2
#define NTT 2048
#define ND 1024
#define NK 8
#define NF 4096
#define NTOK (NB*NTT)        // 4096 tokens
#define LAMBDA_C 0.5f

// Output layout (float units)
#define Y_SZ   (NTOK*ND)
#define LG_OFF Y_SZ
#define SC_OFF (LG_OFF + NTOK*NK)
#define AD_OFF (SC_OFF + NK)

// Workspace layout (4-byte units)
#define WS_CNT    0        // int[8]  (zeroed each call)
#define WS_SEG    8        // int[9]
#define WS_NTILES 17       // int
#define WS_TILEK  32       // int[1024]
#define WS_TILER  1056     // int[1024]
#define WS_PTOK   4096     // int[32768]
#define WS_PCOEF  36864    // float[32768]
#define WS_COEF   69632    // float[NTOK*NK]
#define WS_H      102400   // f16 h buffer (byte offset 409600)

#define BM 64
#define BN 128
#define BK 64
#define SPLITK2 4

typedef float  f32x4 __attribute__((ext_vector_type(4)));
typedef _Float16 f16x8 __attribute__((ext_vector_type(8)));
typedef unsigned int u32x2 __attribute__((ext_vector_type(2)));
typedef unsigned int u32x4 __attribute__((ext_vector_type(4)));

__device__ __forceinline__ unsigned int pkrtz(float a, float b){
    auto h = __builtin_amdgcn_cvt_pkrtz(a, b);
    return __builtin_bit_cast(unsigned int, h);
}
__device__ __forceinline__ float gelu_exact(float v){
    return 0.5f * v * (1.0f + erff(v * 0.70710678118654752440f));
}

// ---------------- gating ----------------
__global__ __launch_bounds__(256) void k_gating(
    const float* __restrict__ x, const float* __restrict__ pl,
    const float* __restrict__ Wt, const float* __restrict__ Wgt,
    const float* __restrict__ Wel, float* __restrict__ out,
    float* __restrict__ coef, int* __restrict__ cnt)
{
    int t = blockIdx.x;
    const float* xt = x + (size_t)t * ND;
    float acc[NK] = {0,0,0,0,0,0,0,0};
    for (int d = threadIdx.x; d < ND; d += 256){
        float xv = xt[d];
        const float4* w = (const float4*)(Wt + (size_t)d * NK);
        float4 w0 = w[0], w1 = w[1];
        acc[0] += xv*w0.x; acc[1] += xv*w0.y; acc[2] += xv*w0.z; acc[3] += xv*w0.w;
        acc[4] += xv*w1.x; acc[5] += xv*w1.y; acc[6] += xv*w1.z; acc[7] += xv*w1.w;
    }
    __shared__ float red[4][NK];
    #pragma unroll
    for (int k = 0; k < NK; k++){
        float v = acc[k];
        #pragma unroll
        for (int off = 32; off; off >>= 1) v += __shfl_down(v, off);
        if ((threadIdx.x & 63) == 0) red[threadIdx.x >> 6][k] = v;
    }
    __syncthreads();
    if (threadIdx.x == 0){
        const float* p = pl + (size_t)t * NK;
        float pv[NK];
        #pragma unroll
        for (int j = 0; j < NK; j++) pv[j] = p[j];
        float lg[NK]; float mx = -1e30f;
        #pragma unroll
        for (int k = 0; k < NK; k++){
            float v = red[0][k] + red[1][k] + red[2][k] + red[3][k];
            #pragma unroll
            for (int j = 0; j < NK; j++) v += pv[j] * Wgt[j*NK + k];
            lg[k] = v; mx = fmaxf(mx, v);
            out[LG_OFF + (size_t)t*NK + k] = v;
        }
        float e[NK]; float s = 0.f;
        #pragma unroll
        for (int k = 0; k < NK; k++){ e[k] = expf(lg[k] - mx); s += e[k]; }
        float g[NK]; float gsum = 0.f;
        #pragma unroll
        for (int k = 0; k < NK; k++){
            float st = e[k] / s;
            float we = 1.f / (1.f + expf(-Wel[k]));
            bool m = st > LAMBDA_C * we;
            g[k] = m ? st : 0.f;
            gsum += g[k];
        }
        float inv = 1.f / (gsum + 1e-6f);
        #pragma unroll
        for (int k = 0; k < NK; k++){
            coef[(size_t)t*NK + k] = g[k] * inv;
            if (g[k] > 0.f) atomicAdd(&cnt[k], 1);
        }
    }
}

// ---------------- scan: per-expert compaction (8 blocks) ----------------
__global__ __launch_bounds__(256) void k_scan(
    const float* __restrict__ coef, int* __restrict__ wsi,
    float* __restrict__ wsf, int pair_cap)
{
    int k = blockIdx.x;
    const int* cnt = wsi + WS_CNT;
    int base = 0;
    for (int j = 0; j < k; j++) base += cnt[j];
    int tid = threadIdx.x, lane = tid & 63, w = tid >> 6;
    __shared__ int wsum[4];
    __shared__ int sbase;
    if (tid == 0){
        sbase = base;
        wsi[WS_SEG + k] = base;
        if (k == NK-1) wsi[WS_SEG + NK] = base + cnt[k];
    }
    __syncthreads();
    int* ptok = wsi + WS_PTOK;
    float* pc = wsf + WS_PCOEF;
    for (int c0 = 0; c0 < NTOK; c0 += 256){
        int t = c0 + tid;
        float c = coef[(size_t)t*NK + k];
        bool m = c > 0.f;
        unsigned long long bal = __ballot(m);
        int pre = __popcll(bal & ((1ull << lane) - 1ull));
        if (lane == 0) wsum[w] = __popcll(bal);
        __syncthreads();
        int b = sbase;
        for (int j = 0; j < w; j++) b += wsum[j];
        if (m){
            int pos = b + pre;
            if (pos < pair_cap){ ptok[pos] = t; pc[pos] = c; }
        }
        __syncthreads();
        if (tid == 0) sbase += wsum[0] + wsum[1] + wsum[2] + wsum[3];
        __syncthreads();
    }
}

// ---------------- tiles + small outputs ----------------
__global__ void k_tiles(int* __restrict__ wsi, float* __restrict__ out, int pair_cap)
{
    if (threadIdx.x == 0 && blockIdx.x == 0){
        const int* cnt = wsi + WS_CNT;
        const int* seg = wsi + WS_SEG;
        int total = 0;
        for (int k = 0; k < NK; k++){ total += cnt[k]; out[SC_OFF + k] = (float)cnt[k]; }
        out[AD_OFF] = (float)total / (float)NTOK;
        int nt = 0;
        for (int k = 0; k < NK; k++){
            int e = min(seg[k+1], pair_cap);
            for (int r = seg[k]; r < e; r += BM){
                wsi[WS_TILEK + nt] = k; wsi[WS_TILER + nt] = r; nt++;
            }
        }
        wsi[WS_NTILES] = nt;
    }
}

// XCD-chunked bijective work partition: blockIdx%8 -> XCD; each XCD owns a
// contiguous item range so same-B-slab m-tiles (adjacent items) share one L2.
#define XCD_PART_LOOP(nwork)                                              \
    int q_ = (nwork) >> 3, rr_ = (nwork) & 7;                             \
    int xcd_ = blockIdx.x & 7;                                            \
    int slot_ = blockIdx.x >> 3;                                          \
    int nslot_ = gridDim.x >> 3;                                          \
    int cntw_ = q_ + (xcd_ < rr_ ? 1 : 0);                                \
    int start_ = xcd_ * q_ + (xcd_ < rr_ ? xcd_ : rr_);                   \
    for (int p_ = slot_; p_ < cntw_; p_ += nslot_)

// ---- shared staging/MFMA building blocks (macros; unique locals) ----
#define STAGE_A_CVT(la_)                                                  \
    {                                                                     \
        unsigned u_[8];                                                   \
        _Pragma("unroll")                                                 \
        for (int j_ = 0; j_ < 8; j_++)                                    \
            u_[j_] = pkrtz(la_[j_>>1][(j_&1)*2], la_[j_>>1][(j_&1)*2+1]); \
        *(u32x4*)(&lds[adst0]) = (u32x4){u_[0],u_[1],u_[2],u_[3]};        \
        *(u32x4*)(&lds[adst1]) = (u32x4){u_[4],u_[5],u_[6],u_[7]};        \
    }

#define STAGE_B_CVT(lb_)                                                  \
    {                                                                     \
        _Pragma("unroll")                                                 \
        for (int i_ = 0; i_ < 2; i_++){                                   \
            unsigned wA_[4], wB_[4];                                      \
            _Pragma("unroll")                                             \
            for (int r2_ = 0; r2_ < 4; r2_++){                            \
                wA_[r2_] = pkrtz(lb_[i_*4+r2_][0], lb_[i_*4+r2_][1]);     \
                wB_[r2_] = pkrtz(lb_[i_*4+r2_][2], lb_[i_*4+r2_][3]);     \
            }                                                             \
            unsigned kq8_ = (unsigned)((bk4 + i_*8) * 8);                 \
            _Pragma("unroll")                                             \
            for (int j_ = 0; j_ < 4; j_++){                               \
                unsigned s0_ = (j_ < 2) ? wA_[1] : wB_[1];                \
                unsigned s1_ = (j_ < 2) ? wA_[0] : wB_[0];                \
                unsigned s2_ = (j_ < 2) ? wA_[3] : wB_[3];                \
                unsigned s3_ = (j_ < 2) ? wA_[2] : wB_[2];                \
                unsigned sel_ = (j_ & 1) ? 0x07060302u : 0x05040100u;     \
                unsigned o0_ = __builtin_amdgcn_perm(s0_, s1_, sel_);     \
                unsigned o1_ = __builtin_amdgcn_perm(s2_, s3_, sel_);     \
                unsigned fswz_ = (unsigned)(((bf4*4 + j_) & 7) << 4);     \
                *(u32x2*)(&lds[bro + (unsigned)j_*128u + (kq8_ ^ fswz_)]) = (u32x2){o0_, o1_}; \
            }                                                             \
        }                                                                 \
    }

#define MFMA_STEP()                                                       \
    {                                                                     \
        _Pragma("unroll")                                                 \
        for (int kk_ = 0; kk_ < 2; kk_++){                                \
            unsigned sb_ = ((unsigned)(kk_*64) + qk16) ^ swzL;            \
            f16x8 a0_ = *(const f16x8*)(&lds[abase + sb_]);               \
            f16x8 a1_ = *(const f16x8*)(&lds[abase + 2048u + sb_]);       \
            _Pragma("unroll")                                             \
            for (int n_ = 0; n_ < 4; n_++){                               \
                f16x8 bb_ = *(const f16x8*)(&lds[bbase + (unsigned)n_*2048u + sb_]); \
                acc[0][n_] = __builtin_amdgcn_mfma_f32_16x16x32_f16(a0_, bb_, acc[0][n_], 0, 0, 0); \
                acc[1][n_] = __builtin_amdgcn_mfma_f32_16x16x32_f16(a1_, bb_, acc[1][n_], 0, 0, 0); \
            }                                                             \
        }                                                                 \
    }

// ---------------- GEMM1 (MFMA f16, depth-2 pipeline): h = gelu(gather(x) @ W1[k] + b1[k]) ----------------
__global__ __launch_bounds__(256, 2) void k_gemm1(
    const float* __restrict__ x, const float* __restrict__ W1,
    const float* __restrict__ b1, const int* __restrict__ wsi,
    unsigned short* __restrict__ hbuf, int pair_cap)
{
    __shared__ char lds[24576];          // A: 64x128B @0, B: 128x128B @8192
    __shared__ int stok[BM];
    const int* seg  = wsi + WS_SEG;
    const int* tk   = wsi + WS_TILEK;
    const int* tr   = wsi + WS_TILER;
    const int* ptok = wsi + WS_PTOK;
    int ntm = wsi[WS_NTILES];
    int nwork = ntm * (NF / BN);
    int tid  = threadIdx.x;
    int lane = tid & 63;
    int w    = tid >> 6;
    int wr = w >> 1, wc = w & 1;
    int l15 = lane & 15, q = lane >> 4;
    unsigned swzL = (unsigned)((lane & 7) << 4);
    unsigned qk16 = (unsigned)(q << 4);
    unsigned abase = (unsigned)(wr*32 + l15) * 128u;
    unsigned bbase = 8192u + (unsigned)(wc*64 + l15) * 128u;
    int arow = tid >> 2, akseg = tid & 3;
    unsigned awz   = (unsigned)((arow & 7) << 4);
    unsigned adst0 = (unsigned)arow*128u + (((unsigned)(akseg*32)) ^ awz);
    unsigned adst1 = (unsigned)arow*128u + (((unsigned)(akseg*32 + 16)) ^ awz);
    int bk4 = tid & 7, bf4 = tid >> 3;
    unsigned bro = 8192u + (unsigned)(bf4*4) * 128u;

#define LOAD_A1(dst_, tt_)                                                \
    { const float* xn_ = xrow + (tt_)*BK;                                 \
      _Pragma("unroll")                                                   \
      for (int i_ = 0; i_ < 4; i_++) dst_[i_] = *(const f32x4*)(xn_ + i_*4); }
#define LOAD_B1(dst_, tt_)                                                \
    { const float* bn_ = bp + (size_t)(tt_)*BK*NF;                        \
      _Pragma("unroll")                                                   \
      for (int i_ = 0; i_ < 2; i_++)                                      \
      _Pragma("unroll")                                                   \
      for (int r2_ = 0; r2_ < 4; r2_++)                                   \
          dst_[i_*4+r2_] = *(const f32x4*)(bn_ + (size_t)((bk4 + i_*8)*4 + r2_)*NF); }

    XCD_PART_LOOP(nwork){
        int widx = start_ + p_;
        int mt = widx % ntm;
        int ft = widx / ntm;
        int kexp = tk[mt];
        int row0 = tr[mt];
        int nrows = min(BM, seg[kexp+1] - row0);
        int f0 = ft * BN;
        __syncthreads();
        if (tid < BM) stok[tid] = (tid < nrows) ? ptok[row0 + tid] : ptok[row0];
        __syncthreads();
        const float* xrow = x + (size_t)stok[arow]*ND + akseg*16;
        const float* bp   = W1 + (size_t)kexp*ND*NF + f0 + bf4*4;
        f32x4 la0[4], lb0[8], la1[4], lb1[8];
        LOAD_A1(la0, 0) LOAD_B1(lb0, 0)
        LOAD_A1(la1, 1) LOAD_B1(lb1, 1)
        f32x4 acc[2][4] = {};
        #pragma unroll 1
        for (int t = 0; t < ND/BK; t += 2){
            // even step: consume gen0
            if (t) __syncthreads();          // prev odd MFMA done reading LDS
            STAGE_A_CVT(la0) STAGE_B_CVT(lb0)
            __syncthreads();
            if (t + 2 < ND/BK){ LOAD_A1(la0, t+2) LOAD_B1(lb0, t+2) }
            MFMA_STEP()
            // odd step: consume gen1
            __syncthreads();
            STAGE_A_CVT(la1) STAGE_B_CVT(lb1)
            __syncthreads();
            if (t + 3 < ND/BK){ LOAD_A1(la1, t+3) LOAD_B1(lb1, t+3) }
            MFMA_STEP()
        }
        const float* b1k = b1 + (size_t)kexp*NF;
        #pragma unroll
        for (int n = 0; n < 4; n++){
            int f = f0 + wc*64 + n*16 + l15;
            float bv = b1k[f];
            #pragma unroll
            for (int m = 0; m < 2; m++){
                int rl = wr*32 + m*16 + q*4;
                #pragma unroll
                for (int i = 0; i < 4; i++){
                    int r = rl + i;
                    if (r < nrows && row0 + r < pair_cap){
                        float v = gelu_exact(acc[m][n][i] + bv);
                        hbuf[(size_t)(row0+r)*NF + f] = (unsigned short)(pkrtz(v, 0.f) & 0xffffu);
                    }
                }
            }
        }
    }
#undef LOAD_A1
#undef LOAD_B1
}

// ---------------- GEMM2 (MFMA f16, depth-2 pipeline, split-K): y += coef*(h @ W2[k] + b2[k]) ----------------
__global__ __launch_bounds__(256, 2) void k_gemm2(
    const unsigned short* __restrict__ hbuf, const float* __restrict__ W2,
    const float* __restrict__ b2, const int* __restrict__ wsi,
    const float* __restrict__ wsf, float* __restrict__ out, int pair_cap)
{
    __shared__ char lds[24576];
    __shared__ int stok[BM];
    __shared__ float scoef[BM];
    const int* seg  = wsi + WS_SEG;
    const int* tk   = wsi + WS_TILEK;
    const int* tr   = wsi + WS_TILER;
    const int* ptok = wsi + WS_PTOK;
    const float* pcoef = wsf + WS_PCOEF;
    int ntm = wsi[WS_NTILES];
    int nwork = ntm * (ND / BN) * SPLITK2;
    int tid  = threadIdx.x;
    int lane = tid & 63;
    int w    = tid >> 6;
    int wr = w >> 1, wc = w & 1;
    int l15 = lane & 15, q = lane >> 4;
    unsigned swzL = (unsigned)((lane & 7) << 4);
    unsigned qk16 = (unsigned)(q << 4);
    unsigned abase = (unsigned)(wr*32 + l15) * 128u;
    unsigned bbase = 8192u + (unsigned)(wc*64 + l15) * 128u;
    int arow = tid >> 2, akseg = tid & 3;
    unsigned awz   = (unsigned)((arow & 7) << 4);
    unsigned adst0 = (unsigned)arow*128u + (((unsigned)(akseg*32)) ^ awz);
    unsigned adst1 = (unsigned)arow*128u + (((unsigned)(akseg*32 + 16)) ^ awz);
    int bk4 = tid & 7, bf4 = tid >> 3;
    unsigned bro = 8192u + (unsigned)(bf4*4) * 128u;
    const int KT = (NF / SPLITK2) / BK;   // 16 k-tiles per split

#define LOAD_A2(dst_, tt_)                                                \
    { const unsigned short* hn_ = hrow + (tt_)*BK;                        \
      dst_[0] = *(const u32x4*)(hn_);                                     \
      dst_[1] = *(const u32x4*)(hn_ + 8); }
#define LOAD_B2(dst_, tt_)                                                \
    { const float* bn_ = bp + (size_t)(tt_)*BK*ND;                        \
      _Pragma("unroll")                                                   \
      for (int i_ = 0; i_ < 2; i_++)                                      \
      _Pragma("unroll")                                                   \
      for (int r2_ = 0; r2_ < 4; r2_++)                                   \
          dst_[i_*4+r2_] = *(const f32x4*)(bn_ + (size_t)((bk4 + i_*8)*4 + r2_)*ND); }

    XCD_PART_LOOP(nwork){
        int widx = start_ + p_;
        int mt = widx % ntm;
        int rest = widx / ntm;
        int dt = rest & 7;
        int sp = rest >> 3;
        int kexp = tk[mt];
        int row0 = tr[mt];
        int nrows = min(BM, seg[kexp+1] - row0);
        int d0 = dt * BN;
        __syncthreads();
        if (tid < BM){
            int r = row0 + tid;
            bool v = (tid < nrows && r < pair_cap);
            stok[tid]  = v ? ptok[r] : 0;
            scoef[tid] = v ? pcoef[r] : 0.f;
        }
        __syncthreads();
        const unsigned short* hrow = hbuf + (size_t)min(row0 + arow, pair_cap-1)*NF + sp*(NF/SPLITK2) + akseg*16;
        const float* bp = W2 + (size_t)kexp*NF*ND + (size_t)sp*(NF/SPLITK2)*ND + d0 + bf4*4;
        u32x4 ha0[2], ha1[2]; f32x4 lb0[8], lb1[8];
        LOAD_A2(ha0, 0) LOAD_B2(lb0, 0)
        LOAD_A2(ha1, 1) LOAD_B2(lb1, 1)
        f32x4 acc[2][4] = {};
        #pragma unroll 1
        for (int t = 0; t < KT; t += 2){
            // even step
            if (t) __syncthreads();
            *(u32x4*)(&lds[adst0]) = ha0[0];
            *(u32x4*)(&lds[adst1]) = ha0[1];
            STAGE_B_CVT(lb0)
            __syncthreads();
            if (t + 2 < KT){ LOAD_A2(ha0, t+2) LOAD_B2(lb0, t+2) }
            MFMA_STEP()
            // odd step
            __syncthreads();
            *(u32x4*)(&lds[adst0]) = ha1[0];
            *(u32x4*)(&lds[adst1]) = ha1[1];
            STAGE_B_CVT(lb1)
            __syncthreads();
            if (t + 3 < KT){ LOAD_A2(ha1, t+3) LOAD_B2(lb1, t+3) }
            MFMA_STEP()
        }
        const float* b2k = b2 + (size_t)kexp*ND;
        #pragma unroll
        for (int n = 0; n < 4; n++){
            int d = d0 + wc*64 + n*16 + l15;
            float bv = (sp == 0) ? b2k[d] : 0.f;
            #pragma unroll
            for (int m = 0; m < 2; m++){
                int rl = wr*32 + m*16 + q*4;
                #pragma unroll
                for (int i = 0; i < 4; i++){
                    int r = rl + i;
                    if (r < nrows && row0 + r < pair_cap){
                        float c = scoef[r];
                        atomicAdd(&out[(size_t)stok[r]*ND + d], c * (acc[m][n][i] + bv));
                    }
                }
            }
        }
    }
#undef LOAD_A2
#undef LOAD_B2
}

extern "C" void kernel_launch(void* const* d_in, const int* in_sizes, int n_in,
                              void* d_out, int out_size, void* d_ws, size_t ws_size,
                              hipStream_t stream)
{
    const float* x   = (const float*)d_in[0];
    const float* pl  = (const float*)d_in[1];
    const float* Wt  = (const float*)d_in[2];
    const float* Wgt = (const float*)d_in[3];
    const float* Wel = (const float*)d_in[4];
    const float* W1  = (const float*)d_in[5];
    const float* b1  = (const float*)d_in[6];
    const float* W2  = (const float*)d_in[7];
    const float* b2  = (const float*)d_in[8];
    float* out = (float*)d_out;
    int* wsi   = (int*)d_ws;
    float* wsf = (float*)d_ws;
    unsigned short* hbuf = (unsigned short*)((char*)d_ws + (size_t)WS_H*4);

    long long avail = (long long)ws_size - (long long)WS_H*4;
    long long cap = avail / ((long long)NF*2);
    if (cap > (long long)NTOK*NK) cap = (long long)NTOK*NK;
    int pair_cap = (int)cap;

    hipMemsetAsync(d_out, 0, (size_t)out_size*sizeof(float), stream);
    hipMemsetAsync(d_ws, 0, 32, stream);   // cnt[8]
    k_gating<<<NTOK, 256, 0, stream>>>(x, pl, Wt, Wgt, Wel, out, wsf + WS_COEF, wsi + WS_CNT);
    if (pair_cap > 0){
        k_scan<<<NK, 256, 0, stream>>>(wsf + WS_COEF, wsi, wsf, pair_cap);
        k_tiles<<<1, 64, 0, stream>>>(wsi, out, pair_cap);
        k_gemm1<<<2048, 256, 0, stream>>>(x, W1, b1, wsi, hbuf, pair_cap);
        k_gemm2<<<2048, 256, 0, stream>>>(hbuf, W2, b2, wsi, wsf, out, pair_cap);
    }
}

// Round 6
// 303.883 us; speedup vs baseline: 1.1063x; 1.1063x over previous
//
#include <hip/hip_runtime.h>
#include <cstdint>
#include <cstddef>

// Problem dims
#define NB 2
#define NTT 2048
#define ND 1024
#define NK 8
#define NF 4096
#define NTOK (NB*NTT)        // 4096 tokens
#define LAMBDA_C 0.5f

// Output layout (float units)
#define Y_SZ   (NTOK*ND)
#define LG_OFF Y_SZ
#define SC_OFF (LG_OFF + NTOK*NK)
#define AD_OFF (SC_OFF + NK)

// Workspace layout (4-byte units)
#define WS_CNT    0        // int[8]  (zeroed each call)
#define WS_SEG    8        // int[9]
#define WS_NTILES 17       // int
#define WS_TILEK  32       // int[1024]
#define WS_TILER  1056     // int[1024]
#define WS_PTOK   4096     // int[32768]
#define WS_PCOEF  36864    // float[32768]
#define WS_COEF   69632    // float[NTOK*NK]
#define WS_X16    102400   // x as f16: 4M elems = 2M float units
#define WS_H      2199552  // f16 h buffer (byte offset 8798208)

#define BM 128
#define BN 128
#define BK 64
#define SPLITK2 4

typedef float  f32x4 __attribute__((ext_vector_type(4)));
typedef _Float16 f16x8 __attribute__((ext_vector_type(8)));
typedef unsigned int u32x2 __attribute__((ext_vector_type(2)));
typedef unsigned int u32x4 __attribute__((ext_vector_type(4)));

__device__ __forceinline__ unsigned int pkrtz(float a, float b){
    auto h = __builtin_amdgcn_cvt_pkrtz(a, b);
    return __builtin_bit_cast(unsigned int, h);
}
__device__ __forceinline__ float gelu_exact(float v){
    return 0.5f * v * (1.0f + erff(v * 0.70710678118654752440f));
}

// ---------------- x -> f16 prepass ----------------
__global__ __launch_bounds__(256) void k_xcast(const float* __restrict__ x,
                                               unsigned short* __restrict__ x16)
{
    int i = (blockIdx.x*256 + threadIdx.x) * 16;   // grid 1024 covers 4M elems
    const f32x4* src = (const f32x4*)(x + i);
    f32x4 v0 = src[0], v1 = src[1], v2 = src[2], v3 = src[3];
    u32x4 o0 = {pkrtz(v0[0],v0[1]), pkrtz(v0[2],v0[3]), pkrtz(v1[0],v1[1]), pkrtz(v1[2],v1[3])};
    u32x4 o1 = {pkrtz(v2[0],v2[1]), pkrtz(v2[2],v2[3]), pkrtz(v3[0],v3[1]), pkrtz(v3[2],v3[3])};
    *(u32x4*)(x16 + i)     = o0;
    *(u32x4*)(x16 + i + 8) = o1;
}

// ---------------- gating ----------------
__global__ __launch_bounds__(256) void k_gating(
    const float* __restrict__ x, const float* __restrict__ pl,
    const float* __restrict__ Wt, const float* __restrict__ Wgt,
    const float* __restrict__ Wel, float* __restrict__ out,
    float* __restrict__ coef, int* __restrict__ cnt)
{
    int t = blockIdx.x;
    const float* xt = x + (size_t)t * ND;
    float acc[NK] = {0,0,0,0,0,0,0,0};
    for (int d = threadIdx.x; d < ND; d += 256){
        float xv = xt[d];
        const float4* w = (const float4*)(Wt + (size_t)d * NK);
        float4 w0 = w[0], w1 = w[1];
        acc[0] += xv*w0.x; acc[1] += xv*w0.y; acc[2] += xv*w0.z; acc[3] += xv*w0.w;
        acc[4] += xv*w1.x; acc[5] += xv*w1.y; acc[6] += xv*w1.z; acc[7] += xv*w1.w;
    }
    __shared__ float red[4][NK];
    #pragma unroll
    for (int k = 0; k < NK; k++){
        float v = acc[k];
        #pragma unroll
        for (int off = 32; off; off >>= 1) v += __shfl_down(v, off);
        if ((threadIdx.x & 63) == 0) red[threadIdx.x >> 6][k] = v;
    }
    __syncthreads();
    if (threadIdx.x == 0){
        const float* p = pl + (size_t)t * NK;
        float pv[NK];
        #pragma unroll
        for (int j = 0; j < NK; j++) pv[j] = p[j];
        float lg[NK]; float mx = -1e30f;
        #pragma unroll
        for (int k = 0; k < NK; k++){
            float v = red[0][k] + red[1][k] + red[2][k] + red[3][k];
            #pragma unroll
            for (int j = 0; j < NK; j++) v += pv[j] * Wgt[j*NK + k];
            lg[k] = v; mx = fmaxf(mx, v);
            out[LG_OFF + (size_t)t*NK + k] = v;
        }
        float e[NK]; float s = 0.f;
        #pragma unroll
        for (int k = 0; k < NK; k++){ e[k] = expf(lg[k] - mx); s += e[k]; }
        float g[NK]; float gsum = 0.f;
        #pragma unroll
        for (int k = 0; k < NK; k++){
            float st = e[k] / s;
            float we = 1.f / (1.f + expf(-Wel[k]));
            bool m = st > LAMBDA_C * we;
            g[k] = m ? st : 0.f;
            gsum += g[k];
        }
        float inv = 1.f / (gsum + 1e-6f);
        #pragma unroll
        for (int k = 0; k < NK; k++){
            coef[(size_t)t*NK + k] = g[k] * inv;
            if (g[k] > 0.f) atomicAdd(&cnt[k], 1);
        }
    }
}

// ---------------- scan: per-expert compaction (8 blocks) ----------------
__global__ __launch_bounds__(256) void k_scan(
    const float* __restrict__ coef, int* __restrict__ wsi,
    float* __restrict__ wsf, int pair_cap)
{
    int k = blockIdx.x;
    const int* cnt = wsi + WS_CNT;
    int base = 0;
    for (int j = 0; j < k; j++) base += cnt[j];
    int tid = threadIdx.x, lane = tid & 63, w = tid >> 6;
    __shared__ int wsum[4];
    __shared__ int sbase;
    if (tid == 0){
        sbase = base;
        wsi[WS_SEG + k] = base;
        if (k == NK-1) wsi[WS_SEG + NK] = base + cnt[k];
    }
    __syncthreads();
    int* ptok = wsi + WS_PTOK;
    float* pc = wsf + WS_PCOEF;
    for (int c0 = 0; c0 < NTOK; c0 += 256){
        int t = c0 + tid;
        float c = coef[(size_t)t*NK + k];
        bool m = c > 0.f;
        unsigned long long bal = __ballot(m);
        int pre = __popcll(bal & ((1ull << lane) - 1ull));
        if (lane == 0) wsum[w] = __popcll(bal);
        __syncthreads();
        int b = sbase;
        for (int j = 0; j < w; j++) b += wsum[j];
        if (m){
            int pos = b + pre;
            if (pos < pair_cap){ ptok[pos] = t; pc[pos] = c; }
        }
        __syncthreads();
        if (tid == 0) sbase += wsum[0] + wsum[1] + wsum[2] + wsum[3];
        __syncthreads();
    }
}

// ---------------- tiles + small outputs ----------------
__global__ void k_tiles(int* __restrict__ wsi, float* __restrict__ out, int pair_cap)
{
    if (threadIdx.x == 0 && blockIdx.x == 0){
        const int* cnt = wsi + WS_CNT;
        const int* seg = wsi + WS_SEG;
        int total = 0;
        for (int k = 0; k < NK; k++){ total += cnt[k]; out[SC_OFF + k] = (float)cnt[k]; }
        out[AD_OFF] = (float)total / (float)NTOK;
        int nt = 0;
        for (int k = 0; k < NK; k++){
            int e = min(seg[k+1], pair_cap);
            for (int r = seg[k]; r < e; r += BM){
                wsi[WS_TILEK + nt] = k; wsi[WS_TILER + nt] = r; nt++;
            }
        }
        wsi[WS_NTILES] = nt;
    }
}

// XCD-chunked bijective work partition
#define XCD_PART_LOOP(nwork)                                              \
    int q_ = (nwork) >> 3, rr_ = (nwork) & 7;                             \
    int xcd_ = blockIdx.x & 7;                                            \
    int slot_ = blockIdx.x >> 3;                                          \
    int nslot_ = gridDim.x >> 3;                                          \
    int cntw_ = q_ + (xcd_ < rr_ ? 1 : 0);                                \
    int start_ = xcd_ * q_ + (xcd_ < rr_ ? xcd_ : rr_);                   \
    for (int p_ = slot_; p_ < cntw_; p_ += nslot_)

// ---- staging/MFMA building blocks ----
// A region: [0,16384) rows 0..127 f16, row r at r*128, granule g at (g*16)^((r&7)<<4)
// B region: [16384,32768) cols 0..127 f16 (k-major per col), same swizzle
#define LOAD_A16(ptr_)                                                    \
    { _Pragma("unroll")                                                   \
      for (int g_ = 0; g_ < 4; g_++) pa[g_] = *(const u32x4*)((ptr_) + g_*8); }

#define STAGE_A_F16()                                                     \
    { _Pragma("unroll")                                                   \
      for (int g_ = 0; g_ < 4; g_++){                                     \
          unsigned off_ = ((unsigned)((axkh*4 + g_)*16)) ^ aswz;          \
          *(u32x4*)(&lds[arowb + off_]) = pa[g_];                         \
      } }

#define STAGE_B_CVT(lb_)                                                  \
    {                                                                     \
        _Pragma("unroll")                                                 \
        for (int i_ = 0; i_ < 2; i_++){                                   \
            unsigned wA_[4], wB_[4];                                      \
            _Pragma("unroll")                                             \
            for (int r2_ = 0; r2_ < 4; r2_++){                            \
                wA_[r2_] = pkrtz(lb_[i_*4+r2_][0], lb_[i_*4+r2_][1]);     \
                wB_[r2_] = pkrtz(lb_[i_*4+r2_][2], lb_[i_*4+r2_][3]);     \
            }                                                             \
            unsigned kq8_ = (unsigned)((bk4 + i_*8) * 8);                 \
            _Pragma("unroll")                                             \
            for (int j_ = 0; j_ < 4; j_++){                               \
                unsigned s0_ = (j_ < 2) ? wA_[1] : wB_[1];                \
                unsigned s1_ = (j_ < 2) ? wA_[0] : wB_[0];                \
                unsigned s2_ = (j_ < 2) ? wA_[3] : wB_[3];                \
                unsigned s3_ = (j_ < 2) ? wA_[2] : wB_[2];                \
                unsigned sel_ = (j_ & 1) ? 0x07060302u : 0x05040100u;     \
                unsigned o0_ = __builtin_amdgcn_perm(s0_, s1_, sel_);     \
                unsigned o1_ = __builtin_amdgcn_perm(s2_, s3_, sel_);     \
                unsigned fswz_ = (unsigned)(((bf4*4 + j_) & 7) << 4);     \
                *(u32x2*)(&lds[bro + (unsigned)j_*128u + (kq8_ ^ fswz_)]) = (u32x2){o0_, o1_}; \
            }                                                             \
        }                                                                 \
    }

#define MFMA_STEP128()                                                    \
    {                                                                     \
        _Pragma("unroll")                                                 \
        for (int kk_ = 0; kk_ < 2; kk_++){                                \
            unsigned sb_ = ((unsigned)(kk_*64) + qk16) ^ swzL;            \
            f16x8 af_[4], bf_[4];                                         \
            _Pragma("unroll")                                             \
            for (int m_ = 0; m_ < 4; m_++) af_[m_] = *(const f16x8*)(&lds[abase + (unsigned)m_*2048u + sb_]); \
            _Pragma("unroll")                                             \
            for (int n_ = 0; n_ < 4; n_++) bf_[n_] = *(const f16x8*)(&lds[bbase + (unsigned)n_*2048u + sb_]); \
            _Pragma("unroll")                                             \
            for (int m_ = 0; m_ < 4; m_++)                                \
            _Pragma("unroll")                                             \
            for (int n_ = 0; n_ < 4; n_++)                                \
                acc[m_][n_] = __builtin_amdgcn_mfma_f32_16x16x32_f16(af_[m_], bf_[n_], acc[m_][n_], 0, 0, 0); \
        }                                                                 \
    }

#define LOAD_B(dst_, tt_, LDW_)                                           \
    { const float* bn_ = bp + (size_t)(tt_)*BK*LDW_;                      \
      _Pragma("unroll")                                                   \
      for (int i_ = 0; i_ < 2; i_++)                                      \
      _Pragma("unroll")                                                   \
      for (int r2_ = 0; r2_ < 4; r2_++)                                   \
          dst_[i_*4+r2_] = *(const f32x4*)(bn_ + (size_t)((bk4 + i_*8)*4 + r2_)*LDW_); }

// ---------------- GEMM1: h = gelu(gather(x16) @ W1[k] + b1[k]) ----------------
__global__ __launch_bounds__(256, 2) void k_gemm1(
    const unsigned short* __restrict__ x16, const float* __restrict__ W1,
    const float* __restrict__ b1, const int* __restrict__ wsi,
    unsigned short* __restrict__ hbuf, int pair_cap)
{
    __shared__ char lds[32768];
    __shared__ int stok[BM];
    const int* seg  = wsi + WS_SEG;
    const int* tk   = wsi + WS_TILEK;
    const int* tr   = wsi + WS_TILER;
    const int* ptok = wsi + WS_PTOK;
    int ntm = wsi[WS_NTILES];
    int nwork = ntm * (NF / BN);
    int tid  = threadIdx.x;
    int lane = tid & 63;
    int w    = tid >> 6;
    int wr = w >> 1, wc = w & 1;
    int l15 = lane & 15, q = lane >> 4;
    unsigned swzL = (unsigned)((l15 & 7) << 4);
    unsigned qk16 = (unsigned)(q << 4);
    unsigned abase = (unsigned)(wr*64 + l15) * 128u;
    unsigned bbase = 16384u + (unsigned)(wc*64 + l15) * 128u;
    int axrow = tid >> 1, axkh = tid & 1;
    unsigned arowb = (unsigned)axrow * 128u;
    unsigned aswz  = (unsigned)((axrow & 7) << 4);
    int bk4 = tid & 7, bf4 = tid >> 3;
    unsigned bro = 16384u + (unsigned)(bf4*4) * 128u;

    XCD_PART_LOOP(nwork){
        int widx = start_ + p_;
        int mt = widx % ntm;
        int ft = widx / ntm;
        int kexp = tk[mt];
        int row0 = tr[mt];
        int nrows = min(BM, seg[kexp+1] - row0);
        int f0 = ft * BN;
        __syncthreads();
        if (tid < BM){
            int r = row0 + tid;
            stok[tid] = (tid < nrows && r < pair_cap) ? ptok[r] : ptok[row0];
        }
        __syncthreads();
        const unsigned short* xrow = x16 + (size_t)stok[axrow]*ND + axkh*32;
        const float* bp = W1 + (size_t)kexp*ND*NF + f0 + bf4*4;
        u32x4 pa[4]; f32x4 pb[8];
        LOAD_A16(xrow) LOAD_B(pb, 0, NF)
        f32x4 acc[4][4] = {};
        for (int t = 0; t < ND/BK; t++){
            if (t) __syncthreads();
            STAGE_A_F16() STAGE_B_CVT(pb)
            __syncthreads();
            if (t + 1 < ND/BK){
                const unsigned short* xn = xrow + (t+1)*BK;
                LOAD_A16(xn) LOAD_B(pb, t+1, NF)
            }
            MFMA_STEP128()
        }
        const float* b1k = b1 + (size_t)kexp*NF;
        #pragma unroll
        for (int n = 0; n < 4; n++){
            int f = f0 + wc*64 + n*16 + l15;
            float bv = b1k[f];
            #pragma unroll
            for (int m = 0; m < 4; m++){
                int rl = wr*64 + m*16 + q*4;
                #pragma unroll
                for (int i = 0; i < 4; i++){
                    int r = rl + i;
                    if (r < nrows && row0 + r < pair_cap){
                        float v = gelu_exact(acc[m][n][i] + bv);
                        hbuf[(size_t)(row0+r)*NF + f] = (unsigned short)(pkrtz(v, 0.f) & 0xffffu);
                    }
                }
            }
        }
    }
}

// ---------------- GEMM2 (split-K): y += coef*(h @ W2[k] + b2[k]) ----------------
__global__ __launch_bounds__(256, 2) void k_gemm2(
    const unsigned short* __restrict__ hbuf, const float* __restrict__ W2,
    const float* __restrict__ b2, const int* __restrict__ wsi,
    const float* __restrict__ wsf, float* __restrict__ out, int pair_cap)
{
    __shared__ char lds[32768];
    __shared__ int stok[BM];
    __shared__ float scoef[BM];
    const int* seg  = wsi + WS_SEG;
    const int* tk   = wsi + WS_TILEK;
    const int* tr   = wsi + WS_TILER;
    const int* ptok = wsi + WS_PTOK;
    const float* pcoef = wsf + WS_PCOEF;
    int ntm = wsi[WS_NTILES];
    int nwork = ntm * (ND / BN) * SPLITK2;
    int tid  = threadIdx.x;
    int lane = tid & 63;
    int w    = tid >> 6;
    int wr = w >> 1, wc = w & 1;
    int l15 = lane & 15, q = lane >> 4;
    unsigned swzL = (unsigned)((l15 & 7) << 4);
    unsigned qk16 = (unsigned)(q << 4);
    unsigned abase = (unsigned)(wr*64 + l15) * 128u;
    unsigned bbase = 16384u + (unsigned)(wc*64 + l15) * 128u;
    int axrow = tid >> 1, axkh = tid & 1;
    unsigned arowb = (unsigned)axrow * 128u;
    unsigned aswz  = (unsigned)((axrow & 7) << 4);
    int bk4 = tid & 7, bf4 = tid >> 3;
    unsigned bro = 16384u + (unsigned)(bf4*4) * 128u;
    const int KT = (NF / SPLITK2) / BK;   // 16

    XCD_PART_LOOP(nwork){
        int widx = start_ + p_;
        int mt = widx % ntm;
        int rest = widx / ntm;
        int dt = rest & 7;
        int sp = rest >> 3;
        int kexp = tk[mt];
        int row0 = tr[mt];
        int nrows = min(BM, seg[kexp+1] - row0);
        int d0 = dt * BN;
        __syncthreads();
        if (tid < BM){
            int r = row0 + tid;
            bool v = (tid < nrows && r < pair_cap);
            stok[tid]  = v ? ptok[r] : 0;
            scoef[tid] = v ? pcoef[r] : 0.f;
        }
        __syncthreads();
        const unsigned short* hrow = hbuf + (size_t)min(row0 + axrow, pair_cap-1)*NF + sp*(NF/SPLITK2) + axkh*32;
        const float* bp = W2 + (size_t)kexp*NF*ND + (size_t)sp*(NF/SPLITK2)*ND + d0 + bf4*4;
        u32x4 pa[4]; f32x4 pb[8];
        LOAD_A16(hrow) LOAD_B(pb, 0, ND)
        f32x4 acc[4][4] = {};
        for (int t = 0; t < KT; t++){
            if (t) __syncthreads();
            STAGE_A_F16() STAGE_B_CVT(pb)
            __syncthreads();
            if (t + 1 < KT){
                const unsigned short* hn = hrow + (t+1)*BK;
                LOAD_A16(hn) LOAD_B(pb, t+1, ND)
            }
            MFMA_STEP128()
        }
        const float* b2k = b2 + (size_t)kexp*ND;
        #pragma unroll
        for (int n = 0; n < 4; n++){
            int d = d0 + wc*64 + n*16 + l15;
            float bv = (sp == 0) ? b2k[d] : 0.f;
            #pragma unroll
            for (int m = 0; m < 4; m++){
                int rl = wr*64 + m*16 + q*4;
                #pragma unroll
                for (int i = 0; i < 4; i++){
                    int r = rl + i;
                    if (r < nrows && row0 + r < pair_cap){
                        float c = scoef[r];
                        atomicAdd(&out[(size_t)stok[r]*ND + d], c * (acc[m][n][i] + bv));
                    }
                }
            }
        }
    }
}

extern "C" void kernel_launch(void* const* d_in, const int* in_sizes, int n_in,
                              void* d_out, int out_size, void* d_ws, size_t ws_size,
                              hipStream_t stream)
{
    const float* x   = (const float*)d_in[0];
    const float* pl  = (const float*)d_in[1];
    const float* Wt  = (const float*)d_in[2];
    const float* Wgt = (const float*)d_in[3];
    const float* Wel = (const float*)d_in[4];
    const float* W1  = (const float*)d_in[5];
    const float* b1  = (const float*)d_in[6];
    const float* W2  = (const float*)d_in[7];
    const float* b2  = (const float*)d_in[8];
    float* out = (float*)d_out;
    int* wsi   = (int*)d_ws;
    float* wsf = (float*)d_ws;
    unsigned short* x16  = (unsigned short*)((char*)d_ws + (size_t)WS_X16*4);
    unsigned short* hbuf = (unsigned short*)((char*)d_ws + (size_t)WS_H*4);

    long long avail = (long long)ws_size - (long long)WS_H*4;
    long long cap = avail / ((long long)NF*2);
    if (cap > (long long)NTOK*NK) cap = (long long)NTOK*NK;
    if (cap < 0) cap = 0;
    int pair_cap = (int)cap;

    hipMemsetAsync(d_out, 0, (size_t)out_size*sizeof(float), stream);
    hipMemsetAsync(d_ws, 0, 32, stream);   // cnt[8]
    k_xcast<<<1024, 256, 0, stream>>>(x, x16);
    k_gating<<<NTOK, 256, 0, stream>>>(x, pl, Wt, Wgt, Wel, out, wsf + WS_COEF, wsi + WS_CNT);
    if (pair_cap > 0){
        k_scan<<<NK, 256, 0, stream>>>(wsf + WS_COEF, wsi, wsf, pair_cap);
        k_tiles<<<1, 64, 0, stream>>>(wsi, out, pair_cap);
        k_gemm1<<<2048, 256, 0, stream>>>(x16, W1, b1, wsi, hbuf, pair_cap);
        k_gemm2<<<2048, 256, 0, stream>>>(hbuf, W2, b2, wsi, wsf, out, pair_cap);
    }
}

// Round 7
// 244.737 us; speedup vs baseline: 1.3736x; 1.2417x over previous
//
#include <hip/hip_runtime.h>
#include <cstdint>
#include <cstddef>

// Problem dims
#define NB 2
#define NTT 2048
#define ND 1024
#define NK 8
#define NF 4096
#define NTOK (NB*NTT)        // 4096 tokens
#define LAMBDA_C 0.5f

// Output layout (float units)
#define Y_SZ   (NTOK*ND)
#define LG_OFF Y_SZ
#define SC_OFF (LG_OFF + NTOK*NK)
#define AD_OFF (SC_OFF + NK)

// Workspace layout (4-byte units)
#define WS_CNT    0        // int[8]  (zeroed each call)
#define WS_SEG    8        // int[9]
#define WS_NTILES 17       // int
#define WS_TILEK  32       // int[1024]
#define WS_TILER  1056     // int[1024]
#define WS_PTOK   4096     // int[32768]
#define WS_PCOEF  36864    // float[32768]
#define WS_COEF   69632    // float[NTOK*NK]
#define WS_X16    102400   // x as f16: 4M elems = 2M float units
#define WS_H      2199552  // f16 h buffer (byte offset 8798208)

#define BM 128
#define BN 64
#define BK 64
#define SPLITK2 4
#define KT 16              // K-steps per item (both gemms)

// LDS offsets (bytes): A slots 2x16KB, B slots 2x8KB
#define AOFF0 0u
#define AOFF1 16384u
#define BOFF0 32768u
#define BOFF1 40960u

typedef float  f32x4 __attribute__((ext_vector_type(4)));
typedef _Float16 f16x8 __attribute__((ext_vector_type(8)));
typedef unsigned int u32x2 __attribute__((ext_vector_type(2)));
typedef unsigned int u32x4 __attribute__((ext_vector_type(4)));

__device__ __forceinline__ unsigned int pkrtz(float a, float b){
    auto h = __builtin_amdgcn_cvt_pkrtz(a, b);
    return __builtin_bit_cast(unsigned int, h);
}
__device__ __forceinline__ float gelu_exact(float v){
    return 0.5f * v * (1.0f + erff(v * 0.70710678118654752440f));
}

// ---------------- x -> f16 prepass ----------------
__global__ __launch_bounds__(256) void k_xcast(const float* __restrict__ x,
                                               unsigned short* __restrict__ x16)
{
    int i = (blockIdx.x*256 + threadIdx.x) * 16;   // grid 1024 covers 4M elems
    const f32x4* src = (const f32x4*)(x + i);
    f32x4 v0 = src[0], v1 = src[1], v2 = src[2], v3 = src[3];
    u32x4 o0 = {pkrtz(v0[0],v0[1]), pkrtz(v0[2],v0[3]), pkrtz(v1[0],v1[1]), pkrtz(v1[2],v1[3])};
    u32x4 o1 = {pkrtz(v2[0],v2[1]), pkrtz(v2[2],v2[3]), pkrtz(v3[0],v3[1]), pkrtz(v3[2],v3[3])};
    *(u32x4*)(x16 + i)     = o0;
    *(u32x4*)(x16 + i + 8) = o1;
}

// ---------------- gating ----------------
__global__ __launch_bounds__(256) void k_gating(
    const float* __restrict__ x, const float* __restrict__ pl,
    const float* __restrict__ Wt, const float* __restrict__ Wgt,
    const float* __restrict__ Wel, float* __restrict__ out,
    float* __restrict__ coef, int* __restrict__ cnt)
{
    int t = blockIdx.x;
    const float* xt = x + (size_t)t * ND;
    float acc[NK] = {0,0,0,0,0,0,0,0};
    for (int d = threadIdx.x; d < ND; d += 256){
        float xv = xt[d];
        const float4* w = (const float4*)(Wt + (size_t)d * NK);
        float4 w0 = w[0], w1 = w[1];
        acc[0] += xv*w0.x; acc[1] += xv*w0.y; acc[2] += xv*w0.z; acc[3] += xv*w0.w;
        acc[4] += xv*w1.x; acc[5] += xv*w1.y; acc[6] += xv*w1.z; acc[7] += xv*w1.w;
    }
    __shared__ float red[4][NK];
    #pragma unroll
    for (int k = 0; k < NK; k++){
        float v = acc[k];
        #pragma unroll
        for (int off = 32; off; off >>= 1) v += __shfl_down(v, off);
        if ((threadIdx.x & 63) == 0) red[threadIdx.x >> 6][k] = v;
    }
    __syncthreads();
    if (threadIdx.x == 0){
        const float* p = pl + (size_t)t * NK;
        float pv[NK];
        #pragma unroll
        for (int j = 0; j < NK; j++) pv[j] = p[j];
        float lg[NK]; float mx = -1e30f;
        #pragma unroll
        for (int k = 0; k < NK; k++){
            float v = red[0][k] + red[1][k] + red[2][k] + red[3][k];
            #pragma unroll
            for (int j = 0; j < NK; j++) v += pv[j] * Wgt[j*NK + k];
            lg[k] = v; mx = fmaxf(mx, v);
            out[LG_OFF + (size_t)t*NK + k] = v;
        }
        float e[NK]; float s = 0.f;
        #pragma unroll
        for (int k = 0; k < NK; k++){ e[k] = expf(lg[k] - mx); s += e[k]; }
        float g[NK]; float gsum = 0.f;
        #pragma unroll
        for (int k = 0; k < NK; k++){
            float st = e[k] / s;
            float we = 1.f / (1.f + expf(-Wel[k]));
            bool m = st > LAMBDA_C * we;
            g[k] = m ? st : 0.f;
            gsum += g[k];
        }
        float inv = 1.f / (gsum + 1e-6f);
        #pragma unroll
        for (int k = 0; k < NK; k++){
            coef[(size_t)t*NK + k] = g[k] * inv;
            if (g[k] > 0.f) atomicAdd(&cnt[k], 1);
        }
    }
}

// ---------------- scan: per-expert compaction (8 blocks) ----------------
__global__ __launch_bounds__(256) void k_scan(
    const float* __restrict__ coef, int* __restrict__ wsi,
    float* __restrict__ wsf, int pair_cap)
{
    int k = blockIdx.x;
    const int* cnt = wsi + WS_CNT;
    int base = 0;
    for (int j = 0; j < k; j++) base += cnt[j];
    int tid = threadIdx.x, lane = tid & 63, w = tid >> 6;
    __shared__ int wsum[4];
    __shared__ int sbase;
    if (tid == 0){
        sbase = base;
        wsi[WS_SEG + k] = base;
        if (k == NK-1) wsi[WS_SEG + NK] = base + cnt[k];
    }
    __syncthreads();
    int* ptok = wsi + WS_PTOK;
    float* pc = wsf + WS_PCOEF;
    for (int c0 = 0; c0 < NTOK; c0 += 256){
        int t = c0 + tid;
        float c = coef[(size_t)t*NK + k];
        bool m = c > 0.f;
        unsigned long long bal = __ballot(m);
        int pre = __popcll(bal & ((1ull << lane) - 1ull));
        if (lane == 0) wsum[w] = __popcll(bal);
        __syncthreads();
        int b = sbase;
        for (int j = 0; j < w; j++) b += wsum[j];
        if (m){
            int pos = b + pre;
            if (pos < pair_cap){ ptok[pos] = t; pc[pos] = c; }
        }
        __syncthreads();
        if (tid == 0) sbase += wsum[0] + wsum[1] + wsum[2] + wsum[3];
        __syncthreads();
    }
}

// ---------------- tiles + small outputs ----------------
__global__ void k_tiles(int* __restrict__ wsi, float* __restrict__ out, int pair_cap)
{
    if (threadIdx.x == 0 && blockIdx.x == 0){
        const int* cnt = wsi + WS_CNT;
        const int* seg = wsi + WS_SEG;
        int total = 0;
        for (int k = 0; k < NK; k++){ total += cnt[k]; out[SC_OFF + k] = (float)cnt[k]; }
        out[AD_OFF] = (float)total / (float)NTOK;
        int nt = 0;
        for (int k = 0; k < NK; k++){
            int e = min(seg[k+1], pair_cap);
            for (int r = seg[k]; r < e; r += BM){
                wsi[WS_TILEK + nt] = k; wsi[WS_TILER + nt] = r; nt++;
            }
        }
        wsi[WS_NTILES] = nt;
    }
}

// XCD-chunked bijective work partition
#define XCD_PART_LOOP(nwork)                                              \
    int q_ = (nwork) >> 3, rr_ = (nwork) & 7;                             \
    int xcd_ = blockIdx.x & 7;                                            \
    int slot_ = blockIdx.x >> 3;                                          \
    int nslot_ = gridDim.x >> 3;                                          \
    int cntw_ = q_ + (xcd_ < rr_ ? 1 : 0);                                \
    int start_ = xcd_ * q_ + (xcd_ < rr_ ? xcd_ : rr_);                   \
    for (int p_ = slot_; p_ < cntw_; p_ += nslot_)

// ---- staging / MFMA building blocks ----
// A LDS slot: 128 rows x 64 f16; row r at r*128B; seg s (16B) at (s^(r&7))*16
// B LDS slot: 64 cols x 64 f16 k-major; col c at c*128B; k-quad kq (8B) at (kq*8)^((c&7)<<4)

#define LOAD_A(dst_, tt_)                                                 \
    { const unsigned short* an_ = asrc + (tt_)*BK;                        \
      _Pragma("unroll")                                                   \
      for (int j_ = 0; j_ < 4; j_++) dst_[j_] = *(const u32x4*)(an_ + j_*8); }

#define LOAD_B(dst_, tt_, LDW_)                                           \
    { const float* bn_ = bsrc + (size_t)((tt_)*BK + bkq*4)*LDW_;          \
      _Pragma("unroll")                                                   \
      for (int r_ = 0; r_ < 4; r_++) dst_[r_] = *(const f32x4*)(bn_ + (size_t)r_*LDW_); }

#define STAGE_A(src_, AO_)                                                \
    { _Pragma("unroll")                                                   \
      for (int j_ = 0; j_ < 4; j_++){                                     \
          unsigned off_ = (AO_) + (unsigned)arow*128u +                   \
              ((((unsigned)(ahalf*4 + j_)) ^ (unsigned)(arow & 7)) << 4); \
          *(u32x4*)(&lds[off_]) = src_[j_];                               \
      } }

#define STAGE_B(src_, BO_)                                                \
    { unsigned wA_[4], wB_[4];                                            \
      _Pragma("unroll")                                                   \
      for (int r_ = 0; r_ < 4; r_++){                                     \
          wA_[r_] = pkrtz(src_[r_][0], src_[r_][1]);                      \
          wB_[r_] = pkrtz(src_[r_][2], src_[r_][3]);                      \
      }                                                                   \
      _Pragma("unroll")                                                   \
      for (int j_ = 0; j_ < 4; j_++){                                     \
          unsigned s0_ = (j_ < 2) ? wA_[1] : wB_[1];                      \
          unsigned s1_ = (j_ < 2) ? wA_[0] : wB_[0];                      \
          unsigned s2_ = (j_ < 2) ? wA_[3] : wB_[3];                      \
          unsigned s3_ = (j_ < 2) ? wA_[2] : wB_[2];                      \
          unsigned sel_ = (j_ & 1) ? 0x07060302u : 0x05040100u;           \
          unsigned o0_ = __builtin_amdgcn_perm(s0_, s1_, sel_);           \
          unsigned o1_ = __builtin_amdgcn_perm(s2_, s3_, sel_);           \
          unsigned col_ = (unsigned)(bcc*4 + j_);                         \
          unsigned off_ = (BO_) + col_*128u +                             \
              (((unsigned)(bkq*8)) ^ ((col_ & 7u) << 4));                 \
          *(u32x2*)(&lds[off_]) = (u32x2){o0_, o1_};                      \
      } }

#define MFMA_RD(AO_, BO_)                                                 \
    { _Pragma("unroll")                                                   \
      for (int kk_ = 0; kk_ < 2; kk_++){                                  \
          unsigned sb_ = ((unsigned)(kk_*64 + q*16)) ^ swzL;              \
          f16x8 af_[4], bf_[2];                                           \
          _Pragma("unroll")                                               \
          for (int m_ = 0; m_ < 4; m_++)                                  \
              af_[m_] = *(const f16x8*)(&lds[(AO_) + (unsigned)(wr*64 + m_*16 + l15)*128u + sb_]); \
          _Pragma("unroll")                                               \
          for (int n_ = 0; n_ < 2; n_++)                                  \
              bf_[n_] = *(const f16x8*)(&lds[(BO_) + (unsigned)(wc*32 + n_*16 + l15)*128u + sb_]); \
          _Pragma("unroll")                                               \
          for (int m_ = 0; m_ < 4; m_++)                                  \
          _Pragma("unroll")                                               \
          for (int n_ = 0; n_ < 2; n_++)                                  \
              acc[m_][n_] = __builtin_amdgcn_mfma_f32_16x16x32_f16(af_[m_], bf_[n_], acc[m_][n_], 0, 0, 0); \
      } }

#define STEP_SYNC()                                                       \
    asm volatile("s_waitcnt lgkmcnt(0)" ::: "memory");                    \
    __builtin_amdgcn_s_barrier();                                         \
    __builtin_amdgcn_sched_barrier(0);

// ---------------- GEMM1: h = gelu(gather(x16) @ W1[k] + b1[k]) ----------------
__global__ __launch_bounds__(256, 3) void k_gemm1(
    const unsigned short* __restrict__ x16, const float* __restrict__ W1,
    const float* __restrict__ b1, const int* __restrict__ wsi,
    unsigned short* __restrict__ hbuf, int pair_cap)
{
    __shared__ char lds[49152];
    __shared__ int stok[BM];
    const int* seg  = wsi + WS_SEG;
    const int* tk   = wsi + WS_TILEK;
    const int* tr   = wsi + WS_TILER;
    const int* ptok = wsi + WS_PTOK;
    int ntm = wsi[WS_NTILES];
    int nwork = ntm * (NF / BN);
    int tid  = threadIdx.x;
    int lane = tid & 63;
    int w    = tid >> 6;
    int wr = w >> 1, wc = w & 1;
    int l15 = lane & 15, q = lane >> 4;
    unsigned swzL = (unsigned)((l15 & 7) << 4);
    int arow = tid >> 1, ahalf = tid & 1;
    int bkq = tid >> 4, bcc = tid & 15;

    XCD_PART_LOOP(nwork){
        int widx = start_ + p_;
        int mt = widx % ntm;
        int ft = widx / ntm;
        int kexp = tk[mt];
        int row0 = tr[mt];
        int nrows = min(BM, seg[kexp+1] - row0);
        int f0 = ft * BN;
        __syncthreads();
        if (tid < BM){
            int r = row0 + tid;
            stok[tid] = (tid < nrows && r < pair_cap) ? ptok[r] : ptok[row0];
        }
        __syncthreads();
        const unsigned short* asrc = x16 + (size_t)stok[arow]*ND + ahalf*32;
        const float* bsrc = W1 + (size_t)kexp*ND*NF + f0 + bcc*4;
        u32x4 ga0[4], ga1[4]; f32x4 gb0[4], gb1[4];
        LOAD_A(ga0, 0) LOAD_B(gb0, 0, NF)
        LOAD_A(ga1, 1) LOAD_B(gb1, 1, NF)
        f32x4 acc[4][2] = {};
        for (int t = 0; t < KT; t += 2){
            // even step: consume gen0 -> slot0
            STAGE_A(ga0, AOFF0) STAGE_B(gb0, BOFF0)
            if (t + 2 < KT){ LOAD_A(ga0, t+2) LOAD_B(gb0, t+2, NF) }
            STEP_SYNC()
            MFMA_RD(AOFF0, BOFF0)
            // odd step: consume gen1 -> slot1
            STAGE_A(ga1, AOFF1) STAGE_B(gb1, BOFF1)
            if (t + 3 < KT){ LOAD_A(ga1, t+3) LOAD_B(gb1, t+3, NF) }
            STEP_SYNC()
            MFMA_RD(AOFF1, BOFF1)
        }
        const float* b1k = b1 + (size_t)kexp*NF;
        #pragma unroll
        for (int n = 0; n < 2; n++){
            int f = f0 + wc*32 + n*16 + l15;
            float bv = b1k[f];
            #pragma unroll
            for (int m = 0; m < 4; m++){
                int rl = wr*64 + m*16 + q*4;
                #pragma unroll
                for (int i = 0; i < 4; i++){
                    int r = rl + i;
                    if (r < nrows && row0 + r < pair_cap){
                        float v = gelu_exact(acc[m][n][i] + bv);
                        hbuf[(size_t)(row0+r)*NF + f] = (unsigned short)(pkrtz(v, 0.f) & 0xffffu);
                    }
                }
            }
        }
    }
}

// ---------------- GEMM2 (split-K): y += coef*(h @ W2[k] + b2[k]) ----------------
__global__ __launch_bounds__(256, 3) void k_gemm2(
    const unsigned short* __restrict__ hbuf, const float* __restrict__ W2,
    const float* __restrict__ b2, const int* __restrict__ wsi,
    const float* __restrict__ wsf, float* __restrict__ out, int pair_cap)
{
    __shared__ char lds[49152];
    __shared__ int stok[BM];
    __shared__ float scoef[BM];
    const int* seg  = wsi + WS_SEG;
    const int* tk   = wsi + WS_TILEK;
    const int* tr   = wsi + WS_TILER;
    const int* ptok = wsi + WS_PTOK;
    const float* pcoef = wsf + WS_PCOEF;
    int ntm = wsi[WS_NTILES];
    int nwork = ntm * (ND / BN) * SPLITK2;   // mt fastest, then dt(16), then sp(4)
    int tid  = threadIdx.x;
    int lane = tid & 63;
    int w    = tid >> 6;
    int wr = w >> 1, wc = w & 1;
    int l15 = lane & 15, q = lane >> 4;
    unsigned swzL = (unsigned)((l15 & 7) << 4);
    int arow = tid >> 1, ahalf = tid & 1;
    int bkq = tid >> 4, bcc = tid & 15;

    XCD_PART_LOOP(nwork){
        int widx = start_ + p_;
        int mt = widx % ntm;
        int rest = widx / ntm;
        int dt = rest & 15;
        int sp = rest >> 4;
        int kexp = tk[mt];
        int row0 = tr[mt];
        int nrows = min(BM, seg[kexp+1] - row0);
        int d0 = dt * BN;
        __syncthreads();
        if (tid < BM){
            int r = row0 + tid;
            bool v = (tid < nrows && r < pair_cap);
            stok[tid]  = v ? ptok[r] : 0;
            scoef[tid] = v ? pcoef[r] : 0.f;
        }
        __syncthreads();
        int hr = row0 + arow; if (hr >= pair_cap) hr = pair_cap - 1;
        const unsigned short* asrc = hbuf + (size_t)hr*NF + sp*(NF/SPLITK2) + ahalf*32;
        const float* bsrc = W2 + (size_t)kexp*NF*ND + (size_t)sp*(NF/SPLITK2)*ND + d0 + bcc*4;
        u32x4 ga0[4], ga1[4]; f32x4 gb0[4], gb1[4];
        LOAD_A(ga0, 0) LOAD_B(gb0, 0, ND)
        LOAD_A(ga1, 1) LOAD_B(gb1, 1, ND)
        f32x4 acc[4][2] = {};
        for (int t = 0; t < KT; t += 2){
            STAGE_A(ga0, AOFF0) STAGE_B(gb0, BOFF0)
            if (t + 2 < KT){ LOAD_A(ga0, t+2) LOAD_B(gb0, t+2, ND) }
            STEP_SYNC()
            MFMA_RD(AOFF0, BOFF0)
            STAGE_A(ga1, AOFF1) STAGE_B(gb1, BOFF1)
            if (t + 3 < KT){ LOAD_A(ga1, t+3) LOAD_B(gb1, t+3, ND) }
            STEP_SYNC()
            MFMA_RD(AOFF1, BOFF1)
        }
        const float* b2k = b2 + (size_t)kexp*ND;
        #pragma unroll
        for (int n = 0; n < 2; n++){
            int d = d0 + wc*32 + n*16 + l15;
            float bv = (sp == 0) ? b2k[d] : 0.f;
            #pragma unroll
            for (int m = 0; m < 4; m++){
                int rl = wr*64 + m*16 + q*4;
                #pragma unroll
                for (int i = 0; i < 4; i++){
                    int r = rl + i;
                    if (r < nrows && row0 + r < pair_cap){
                        float c = scoef[r];
                        atomicAdd(&out[(size_t)stok[r]*ND + d], c * (acc[m][n][i] + bv));
                    }
                }
            }
        }
    }
}

extern "C" void kernel_launch(void* const* d_in, const int* in_sizes, int n_in,
                              void* d_out, int out_size, void* d_ws, size_t ws_size,
                              hipStream_t stream)
{
    const float* x   = (const float*)d_in[0];
    const float* pl  = (const float*)d_in[1];
    const float* Wt  = (const float*)d_in[2];
    const float* Wgt = (const float*)d_in[3];
    const float* Wel = (const float*)d_in[4];
    const float* W1  = (const float*)d_in[5];
    const float* b1  = (const float*)d_in[6];
    const float* W2  = (const float*)d_in[7];
    const float* b2  = (const float*)d_in[8];
    float* out = (float*)d_out;
    int* wsi   = (int*)d_ws;
    float* wsf = (float*)d_ws;
    unsigned short* x16  = (unsigned short*)((char*)d_ws + (size_t)WS_X16*4);
    unsigned short* hbuf = (unsigned short*)((char*)d_ws + (size_t)WS_H*4);

    long long avail = (long long)ws_size - (long long)WS_H*4;
    long long cap = avail / ((long long)NF*2);
    if (cap > (long long)NTOK*NK) cap = (long long)NTOK*NK;
    if (cap < 0) cap = 0;
    int pair_cap = (int)cap;

    hipMemsetAsync(d_out, 0, (size_t)out_size*sizeof(float), stream);
    hipMemsetAsync(d_ws, 0, 32, stream);   // cnt[8]
    k_xcast<<<1024, 256, 0, stream>>>(x, x16);
    k_gating<<<NTOK, 256, 0, stream>>>(x, pl, Wt, Wgt, Wel, out, wsf + WS_COEF, wsi + WS_CNT);
    if (pair_cap > 0){
        k_scan<<<NK, 256, 0, stream>>>(wsf + WS_COEF, wsi, wsf, pair_cap);
        k_tiles<<<1, 64, 0, stream>>>(wsi, out, pair_cap);
        k_gemm1<<<2048, 256, 0, stream>>>(x16, W1, b1, wsi, hbuf, pair_cap);
        k_gemm2<<<2048, 256, 0, stream>>>(hbuf, W2, b2, wsi, wsf, out, pair_cap);
    }
}